// Round 1
// baseline (692.454 us; speedup 1.0000x reference)
//
#include <hip/hip_runtime.h>
#include <hip/hip_bf16.h>

// ---------- helpers ----------
__device__ __forceinline__ float bfbits2f(unsigned short s) {
    union { unsigned int u; float f; } cv;
    cv.u = ((unsigned int)s) << 16;
    return cv.f;
}
__device__ __forceinline__ unsigned short f2bfbits(float f) {
    union { float f; unsigned int u; } cv; cv.f = f;
    unsigned int u = cv.u;
    u += 0x7fffu + ((u >> 16) & 1u);   // round-to-nearest-even
    return (unsigned short)(u >> 16);
}

// ---------- GEMM: C[M,128] = A[M,128] @ W[128,128]^T + bias ----------
// block 256 threads, tile 64 rows x 64 cols, 4x4 register blocking.
template<bool OUT_BF16>
__global__ __launch_bounds__(256)
void gemm128_bias(const float* __restrict__ A, const float* __restrict__ W,
                  const float* __restrict__ bias, void* __restrict__ Cout, int M)
{
    __shared__ float As[64 * 132];
    __shared__ float Ws[64 * 132];
    const int t  = threadIdx.x;
    const int tx = t & 15;        // col group
    const int ty = t >> 4;        // row group 0..15
    const int row0 = blockIdx.x * 64;
    const int col0 = blockIdx.y * 64;

    // stage A tile (64 rows x 128 k), float4 per step
    for (int j = t; j < 64 * 32; j += 256) {
        int r = j >> 5, kq = (j & 31) * 4;
        float4 v = make_float4(0.f, 0.f, 0.f, 0.f);
        int gr = row0 + r;
        if (gr < M) v = *reinterpret_cast<const float4*>(&A[(size_t)gr * 128 + kq]);
        *reinterpret_cast<float4*>(&As[r * 132 + kq]) = v;
    }
    // stage W tile (rows of W == output cols)
    for (int j = t; j < 64 * 32; j += 256) {
        int r = j >> 5, kq = (j & 31) * 4;
        float4 v = *reinterpret_cast<const float4*>(&W[(size_t)(col0 + r) * 128 + kq]);
        *reinterpret_cast<float4*>(&Ws[r * 132 + kq]) = v;
    }
    __syncthreads();

    float acc[4][4];
    #pragma unroll
    for (int i = 0; i < 4; i++)
        #pragma unroll
        for (int j = 0; j < 4; j++) acc[i][j] = 0.f;

    #pragma unroll 4
    for (int k = 0; k < 128; k += 4) {
        float4 a[4], w[4];
        #pragma unroll
        for (int i = 0; i < 4; i++)
            a[i] = *reinterpret_cast<const float4*>(&As[(i * 16 + ty) * 132 + k]);
        #pragma unroll
        for (int j = 0; j < 4; j++)
            w[j] = *reinterpret_cast<const float4*>(&Ws[(j * 16 + tx) * 132 + k]);
        #pragma unroll
        for (int i = 0; i < 4; i++)
            #pragma unroll
            for (int j = 0; j < 4; j++)
                acc[i][j] += a[i].x * w[j].x + a[i].y * w[j].y
                           + a[i].z * w[j].z + a[i].w * w[j].w;
    }

    #pragma unroll
    for (int i = 0; i < 4; i++) {
        int gr = row0 + i * 16 + ty;
        if (gr >= M) continue;
        #pragma unroll
        for (int j = 0; j < 4; j++) {
            int gc = col0 + j * 16 + tx;
            float vv = acc[i][j] + bias[gc];
            if (OUT_BF16) ((unsigned short*)Cout)[(size_t)gr * 128 + gc] = f2bfbits(vv);
            else          ((float*)Cout)[(size_t)gr * 128 + gc] = vv;
        }
    }
}

// ---------- CSR build ----------
__global__ void hist_kernel(const int* __restrict__ ei, int* __restrict__ counts, int E)
{
    int e = blockIdx.x * blockDim.x + threadIdx.x;
    if (e < E) atomicAdd(&counts[ei[2 * e + 1]], 1);
}

__global__ __launch_bounds__(1024)
void scan_kernel(const int* __restrict__ counts, int* __restrict__ offsets, int n)
{
    __shared__ int wsum[16];
    __shared__ int woff[16];
    __shared__ int ctot;
    const int t = threadIdx.x;
    const int lane = t & 63, w = t >> 6;
    int carry = 0;
    for (int base = 0; base < n; base += 1024) {
        int i = base + t;
        int x = (i < n) ? counts[i] : 0;
        int v = x;
        #pragma unroll
        for (int off = 1; off < 64; off <<= 1) {
            int y = __shfl_up(v, off);
            if (lane >= off) v += y;
        }
        if (lane == 63) wsum[w] = v;
        __syncthreads();
        if (t == 0) {
            int s = 0;
            #pragma unroll
            for (int j = 0; j < 16; j++) { int tmp = wsum[j]; woff[j] = s; s += tmp; }
            ctot = s;
        }
        __syncthreads();
        if (i < n) offsets[i] = carry + woff[w] + v - x;   // exclusive
        carry += ctot;
        __syncthreads();   // protect wsum/woff/ctot before next chunk
    }
    if (t == 0) offsets[n] = carry;
}

__global__ void scatter_kernel(const int* __restrict__ ei, const int* __restrict__ offsets,
                               int* __restrict__ fill, int* __restrict__ sorted_r, int E)
{
    int e = blockIdx.x * blockDim.x + threadIdx.x;
    if (e < E) {
        int c = ei[2 * e + 1];
        int pos = offsets[c] + atomicAdd(&fill[c], 1);
        sorted_r[pos] = ei[2 * e];
    }
}

// ---------- edge attention: one wave per destination node ----------
__global__ __launch_bounds__(256)
void edge_attn_kernel(const unsigned short* __restrict__ qb,
                      const unsigned short* __restrict__ kb,
                      const unsigned short* __restrict__ vb,
                      const int* __restrict__ offsets,
                      const int* __restrict__ sorted_r,
                      float* __restrict__ acc_out, int n)
{
    const int lane = threadIdx.x & 63;
    const int wid  = threadIdx.x >> 6;
    const int node = blockIdx.x * 4 + wid;
    if (node >= n) return;

    const int h    = lane & 7;    // head (score phase)
    const int eloc = lane >> 3;   // edge slot 0..7
    const int seg0 = offsets[node];
    const int segL = offsets[node + 1] - seg0;

    // q fragment: q[node, h*16 .. h*16+15]
    float qf[16];
    {
        const uint4* p = reinterpret_cast<const uint4*>(&qb[(size_t)node * 128 + h * 16]);
        uint4 u0 = p[0], u1 = p[1];
        unsigned int uu[8] = {u0.x, u0.y, u0.z, u0.w, u1.x, u1.y, u1.z, u1.w};
        #pragma unroll
        for (int i = 0; i < 8; i++) {
            qf[2 * i]     = bfbits2f((unsigned short)(uu[i] & 0xffffu));
            qf[2 * i + 1] = bfbits2f((unsigned short)(uu[i] >> 16));
        }
    }

    float acc0 = 0.f, acc1 = 0.f, ssum = 0.f;
    for (int base = 0; base < segL; base += 8) {
        int idx = base + eloc;
        bool valid = idx < segL;
        int r = valid ? sorted_r[seg0 + idx] : 0;

        float ex = 0.f;
        {
            const uint4* p = reinterpret_cast<const uint4*>(&kb[(size_t)r * 128 + h * 16]);
            uint4 u0 = p[0], u1 = p[1];
            unsigned int uu[8] = {u0.x, u0.y, u0.z, u0.w, u1.x, u1.y, u1.z, u1.w};
            float s = 0.f;
            #pragma unroll
            for (int i = 0; i < 8; i++) {
                s += qf[2 * i]     * bfbits2f((unsigned short)(uu[i] & 0xffffu));
                s += qf[2 * i + 1] * bfbits2f((unsigned short)(uu[i] >> 16));
            }
            ex = valid ? __expf(s * 0.25f) : 0.f;   // 1/sqrt(16) = 0.25
        }
        ssum += ex;

        int ecnt = segL - base; if (ecnt > 8) ecnt = 8;
        for (int e = 0; e < ecnt; e++) {
            float exv = __shfl(ex, e * 8 + (lane >> 3));
            int   re  = __shfl(r, e * 8);
            unsigned int u = *reinterpret_cast<const unsigned int*>(&vb[(size_t)re * 128 + 2 * lane]);
            acc0 += exv * bfbits2f((unsigned short)(u & 0xffffu));
            acc1 += exv * bfbits2f((unsigned short)(u >> 16));
        }
    }

    // ssum currently per (eloc,h); reduce over eloc (xor bits 3,4,5)
    ssum += __shfl_xor(ssum, 8);
    ssum += __shfl_xor(ssum, 16);
    ssum += __shfl_xor(ssum, 32);
    // this lane accumulates dims d=2*lane,2*lane+1 -> head = lane>>3; denom lives in lane (lane>>3)
    float den = __shfl(ssum, lane >> 3) + 1e-16f;

    float2 o;
    o.x = acc0 / den;
    o.y = acc1 / den;
    *reinterpret_cast<float2*>(&acc_out[(size_t)node * 128 + 2 * lane]) = o;
}

// ---------- launch ----------
extern "C" void kernel_launch(void* const* d_in, const int* in_sizes, int n_in,
                              void* d_out, int out_size, void* d_ws, size_t ws_size,
                              hipStream_t stream)
{
    const float* feats = (const float*)d_in[0];
    const int*   ei    = (const int*)d_in[1];   // edge_index as int32 pairs [r, c]
    const float* Wq = (const float*)d_in[3];
    const float* bq = (const float*)d_in[4];
    const float* Wk = (const float*)d_in[5];
    const float* bk = (const float*)d_in[6];
    const float* Wv = (const float*)d_in[7];
    const float* bv = (const float*)d_in[8];
    const float* Wo = (const float*)d_in[9];
    const float* bo = (const float*)d_in[10];
    float* out = (float*)d_out;

    const int N = in_sizes[0] / 128;
    const int E = in_sizes[1] / 2;

    char* ws = (char*)d_ws;
    size_t off = 0;
    auto alloc = [&](size_t bytes) -> void* {
        void* p = ws + off;
        off += (bytes + 255) & ~(size_t)255;
        return p;
    };
    unsigned short* qb   = (unsigned short*)alloc((size_t)N * 128 * 2);
    unsigned short* kb   = (unsigned short*)alloc((size_t)N * 128 * 2);
    unsigned short* vb   = (unsigned short*)alloc((size_t)N * 128 * 2);
    float*          accb = (float*)alloc((size_t)N * 128 * 4);
    int* counts   = (int*)alloc(((size_t)N + 1 + N) * 4);  // counts + fill contiguous
    int* fill     = counts + (N + 1);
    int* offsets  = (int*)alloc(((size_t)N + 1) * 4);
    int* sorted_r = (int*)alloc((size_t)E * 4);

    hipMemsetAsync(counts, 0, ((size_t)N + 1 + N) * 4, stream);

    dim3 gg((N + 63) / 64, 2);
    gemm128_bias<true><<<gg, 256, 0, stream>>>(feats, Wq, bq, qb, N);
    gemm128_bias<true><<<gg, 256, 0, stream>>>(feats, Wk, bk, kb, N);
    gemm128_bias<true><<<gg, 256, 0, stream>>>(feats, Wv, bv, vb, N);

    hist_kernel<<<(E + 255) / 256, 256, 0, stream>>>(ei, counts, E);
    scan_kernel<<<1, 1024, 0, stream>>>(counts, offsets, N);
    scatter_kernel<<<(E + 255) / 256, 256, 0, stream>>>(ei, offsets, fill, sorted_r, E);

    edge_attn_kernel<<<(N + 3) / 4, 256, 0, stream>>>(qb, kb, vb, offsets, sorted_r, accb, N);

    gemm128_bias<false><<<gg, 256, 0, stream>>>(accb, Wo, bo, out, N);
}

// Round 2
// 502.136 us; speedup vs baseline: 1.3790x; 1.3790x over previous
//
#include <hip/hip_runtime.h>
#include <hip/hip_bf16.h>

typedef __attribute__((ext_vector_type(8))) short bh8;
typedef __attribute__((ext_vector_type(4))) float f32x4;

__device__ __forceinline__ float bfbits2f(unsigned short s) {
    union { unsigned int u; float f; } cv;
    cv.u = ((unsigned int)s) << 16;
    return cv.f;
}
__device__ __forceinline__ unsigned short f2bfbits(float f) {
    union { float f; unsigned int u; } cv; cv.f = f;
    unsigned int u = cv.u;
    u += 0x7fffu + ((u >> 16) & 1u);   // round-to-nearest-even
    return (unsigned short)(u >> 16);
}

// load 8 consecutive fp32, convert to a bf16x8 MFMA fragment
__device__ __forceinline__ bh8 load_frag_f32(const float* __restrict__ p) {
    float4 f0 = *reinterpret_cast<const float4*>(p);
    float4 f1 = *reinterpret_cast<const float4*>(p + 4);
    bh8 r;
    r[0] = (short)f2bfbits(f0.x); r[1] = (short)f2bfbits(f0.y);
    r[2] = (short)f2bfbits(f0.z); r[3] = (short)f2bfbits(f0.w);
    r[4] = (short)f2bfbits(f1.x); r[5] = (short)f2bfbits(f1.y);
    r[6] = (short)f2bfbits(f1.z); r[7] = (short)f2bfbits(f1.w);
    return r;
}

// ---------- fused QKV GEMM: q/k/v[M,128] = A[M,128] @ W*.T + b*, bf16 out ----------
// block 256 = 4 waves; wave w: rows bx*128+w*32 .. +31, cols by*64 .. +63.
// MFMA 16x16x32 bf16. A-fragments loaded once, reused for Wq/Wk/Wv.
__global__ __launch_bounds__(256)
void qkv_gemm(const float* __restrict__ A,
              const float* __restrict__ Wq, const float* __restrict__ bq,
              const float* __restrict__ Wk, const float* __restrict__ bk,
              const float* __restrict__ Wv, const float* __restrict__ bv,
              unsigned short* __restrict__ Oq, unsigned short* __restrict__ Ok,
              unsigned short* __restrict__ Ov, int M)
{
    const int lane = threadIdx.x & 63;
    const int w    = threadIdx.x >> 6;
    const int r0   = blockIdx.x * 128 + w * 32;
    const int c0   = blockIdx.y * 64;
    const int lr   = lane & 15;         // row within A-tile / col within B,C-tile
    const int lk   = (lane >> 4) * 8;   // k-offset within 32

    bh8 a[2][4];
    #pragma unroll
    for (int rt = 0; rt < 2; rt++) {
        int row = r0 + rt * 16 + lr; if (row >= M) row = M - 1;
        const float* ap = &A[(size_t)row * 128 + lk];
        #pragma unroll
        for (int ks = 0; ks < 4; ks++) a[rt][ks] = load_frag_f32(ap + ks * 32);
    }

    const float* Ws[3] = {Wq, Wk, Wv};
    const float* Bs[3] = {bq, bk, bv};
    unsigned short* Os[3] = {Oq, Ok, Ov};

    #pragma unroll
    for (int wsel = 0; wsel < 3; wsel++) {
        const float* W = Ws[wsel];
        f32x4 acc[2][4];
        #pragma unroll
        for (int rt = 0; rt < 2; rt++)
            #pragma unroll
            for (int ct = 0; ct < 4; ct++)
                #pragma unroll
                for (int q = 0; q < 4; q++) acc[rt][ct][q] = 0.f;

        #pragma unroll
        for (int ks = 0; ks < 4; ks++) {
            bh8 b[4];
            #pragma unroll
            for (int ct = 0; ct < 4; ct++)
                b[ct] = load_frag_f32(&W[(size_t)(c0 + ct * 16 + lr) * 128 + ks * 32 + lk]);
            #pragma unroll
            for (int rt = 0; rt < 2; rt++)
                #pragma unroll
                for (int ct = 0; ct < 4; ct++)
                    acc[rt][ct] = __builtin_amdgcn_mfma_f32_16x16x32_bf16(
                        a[rt][ks], b[ct], acc[rt][ct], 0, 0, 0);
        }

        const float* bias = Bs[wsel];
        unsigned short* O = Os[wsel];
        #pragma unroll
        for (int ct = 0; ct < 4; ct++) {
            float bval = bias[c0 + ct * 16 + lr];
            #pragma unroll
            for (int rt = 0; rt < 2; rt++) {
                int rbase = r0 + rt * 16 + (lane >> 4) * 4;
                #pragma unroll
                for (int reg = 0; reg < 4; reg++) {
                    int row = rbase + reg;
                    if (row < M)
                        O[(size_t)row * 128 + c0 + ct * 16 + lr] = f2bfbits(acc[rt][ct][reg] + bval);
                }
            }
        }
    }
}

// ---------- output GEMM: out[M,128] = Abf16[M,128] @ Wo.T + bo, fp32 out ----------
__global__ __launch_bounds__(256)
void out_gemm(const unsigned short* __restrict__ A, const float* __restrict__ W,
              const float* __restrict__ bias, float* __restrict__ O, int M)
{
    const int lane = threadIdx.x & 63;
    const int w    = threadIdx.x >> 6;
    const int r0   = blockIdx.x * 128 + w * 32;
    const int c0   = blockIdx.y * 64;
    const int lr   = lane & 15;
    const int lk   = (lane >> 4) * 8;

    bh8 a[2][4];
    #pragma unroll
    for (int rt = 0; rt < 2; rt++) {
        int row = r0 + rt * 16 + lr; if (row >= M) row = M - 1;
        const unsigned short* ap = &A[(size_t)row * 128 + lk];
        #pragma unroll
        for (int ks = 0; ks < 4; ks++)
            a[rt][ks] = *reinterpret_cast<const bh8*>(ap + ks * 32);
    }

    f32x4 acc[2][4];
    #pragma unroll
    for (int rt = 0; rt < 2; rt++)
        #pragma unroll
        for (int ct = 0; ct < 4; ct++)
            #pragma unroll
            for (int q = 0; q < 4; q++) acc[rt][ct][q] = 0.f;

    #pragma unroll
    for (int ks = 0; ks < 4; ks++) {
        bh8 b[4];
        #pragma unroll
        for (int ct = 0; ct < 4; ct++)
            b[ct] = load_frag_f32(&W[(size_t)(c0 + ct * 16 + lr) * 128 + ks * 32 + lk]);
        #pragma unroll
        for (int rt = 0; rt < 2; rt++)
            #pragma unroll
            for (int ct = 0; ct < 4; ct++)
                acc[rt][ct] = __builtin_amdgcn_mfma_f32_16x16x32_bf16(
                    a[rt][ks], b[ct], acc[rt][ct], 0, 0, 0);
    }

    #pragma unroll
    for (int ct = 0; ct < 4; ct++) {
        float bval = bias[c0 + ct * 16 + lr];
        #pragma unroll
        for (int rt = 0; rt < 2; rt++) {
            int rbase = r0 + rt * 16 + (lane >> 4) * 4;
            #pragma unroll
            for (int reg = 0; reg < 4; reg++) {
                int row = rbase + reg;
                if (row < M)
                    O[(size_t)row * 128 + c0 + ct * 16 + lr] = acc[rt][ct][reg] + bval;
            }
        }
    }
}

// ---------- CSR build ----------
__global__ void hist_kernel(const int* __restrict__ ei, int* __restrict__ counts, int E)
{
    int e = blockIdx.x * blockDim.x + threadIdx.x;
    if (e < E) atomicAdd(&counts[ei[2 * e + 1]], 1);
}

__device__ __forceinline__ int wave_incl_scan(int v, int lane) {
    #pragma unroll
    for (int off = 1; off < 64; off <<= 1) {
        int y = __shfl_up(v, off);
        if (lane >= off) v += y;
    }
    return v;
}

__global__ __launch_bounds__(1024)
void scan1_kernel(const int* __restrict__ counts, int* __restrict__ offs,
                  int* __restrict__ blkSum, int n)
{
    __shared__ int wsum[16];
    __shared__ int woff[16];
    const int t = threadIdx.x, lane = t & 63, w = t >> 6;
    int i = blockIdx.x * 1024 + t;
    int x = (i < n) ? counts[i] : 0;
    int v = wave_incl_scan(x, lane);
    if (lane == 63) wsum[w] = v;
    __syncthreads();
    if (t == 0) {
        int s = 0;
        #pragma unroll
        for (int j = 0; j < 16; j++) { int tmp = wsum[j]; woff[j] = s; s += tmp; }
        blkSum[blockIdx.x] = s;
    }
    __syncthreads();
    if (i < n) offs[i] = woff[w] + v - x;   // block-local exclusive
}

__global__ void scan2_kernel(const int* __restrict__ blkSum, int* __restrict__ blkOff,
                             int* __restrict__ offs, int nb, int n)
{
    const int lane = threadIdx.x;   // 64 threads
    int carry = 0;
    for (int base = 0; base < nb; base += 64) {
        int x = (base + lane < nb) ? blkSum[base + lane] : 0;
        int v = wave_incl_scan(x, lane);
        if (base + lane < nb) blkOff[base + lane] = carry + v - x;
        carry += __shfl(v, 63);
    }
    if (lane == 0) offs[n] = carry;
}

__global__ __launch_bounds__(1024)
void scan3_kernel(int* __restrict__ offs, const int* __restrict__ blkOff, int n)
{
    int i = blockIdx.x * 1024 + threadIdx.x;
    if (i < n) offs[i] += blkOff[blockIdx.x];
}

__global__ void scatter_kernel(const int* __restrict__ ei, const int* __restrict__ offsets,
                               int* __restrict__ fill, int* __restrict__ sorted_r, int E)
{
    int e = blockIdx.x * blockDim.x + threadIdx.x;
    if (e < E) {
        int c = ei[2 * e + 1];
        int pos = offsets[c] + atomicAdd(&fill[c], 1);
        sorted_r[pos] = ei[2 * e];
    }
}

// ---------- edge attention: one wave per destination node ----------
__global__ __launch_bounds__(256)
void edge_attn_kernel(const unsigned short* __restrict__ qb,
                      const unsigned short* __restrict__ kb,
                      const unsigned short* __restrict__ vb,
                      const int* __restrict__ offsets,
                      const int* __restrict__ sorted_r,
                      unsigned short* __restrict__ acc_out, int n)
{
    const int lane = threadIdx.x & 63;
    const int wid  = threadIdx.x >> 6;
    const int node = blockIdx.x * 4 + wid;
    if (node >= n) return;

    const int h    = lane & 7;    // head (score phase)
    const int eloc = lane >> 3;   // edge slot 0..7
    const int seg0 = offsets[node];
    const int segL = offsets[node + 1] - seg0;

    float qf[16];
    {
        const uint4* p = reinterpret_cast<const uint4*>(&qb[(size_t)node * 128 + h * 16]);
        uint4 u0 = p[0], u1 = p[1];
        unsigned int uu[8] = {u0.x, u0.y, u0.z, u0.w, u1.x, u1.y, u1.z, u1.w};
        #pragma unroll
        for (int i = 0; i < 8; i++) {
            qf[2 * i]     = bfbits2f((unsigned short)(uu[i] & 0xffffu));
            qf[2 * i + 1] = bfbits2f((unsigned short)(uu[i] >> 16));
        }
    }

    float acc0 = 0.f, acc1 = 0.f, ssum = 0.f;
    for (int base = 0; base < segL; base += 8) {
        int idx = base + eloc;
        bool valid = idx < segL;
        int r = valid ? sorted_r[seg0 + idx] : 0;

        float ex = 0.f;
        {
            const uint4* p = reinterpret_cast<const uint4*>(&kb[(size_t)r * 128 + h * 16]);
            uint4 u0 = p[0], u1 = p[1];
            unsigned int uu[8] = {u0.x, u0.y, u0.z, u0.w, u1.x, u1.y, u1.z, u1.w};
            float s = 0.f;
            #pragma unroll
            for (int i = 0; i < 8; i++) {
                s += qf[2 * i]     * bfbits2f((unsigned short)(uu[i] & 0xffffu));
                s += qf[2 * i + 1] * bfbits2f((unsigned short)(uu[i] >> 16));
            }
            ex = valid ? __expf(s * 0.25f) : 0.f;   // 1/sqrt(16) = 0.25
        }
        ssum += ex;

        int ecnt = segL - base; if (ecnt > 8) ecnt = 8;
        for (int e = 0; e < ecnt; e++) {
            float exv = __shfl(ex, e * 8 + (lane >> 3));
            int   re  = __shfl(r, e * 8);
            unsigned int u = *reinterpret_cast<const unsigned int*>(&vb[(size_t)re * 128 + 2 * lane]);
            acc0 += exv * bfbits2f((unsigned short)(u & 0xffffu));
            acc1 += exv * bfbits2f((unsigned short)(u >> 16));
        }
    }

    ssum += __shfl_xor(ssum, 8);
    ssum += __shfl_xor(ssum, 16);
    ssum += __shfl_xor(ssum, 32);
    float den = __shfl(ssum, lane >> 3) + 1e-16f;

    float o0 = acc0 / den, o1 = acc1 / den;
    unsigned int pk = (unsigned int)f2bfbits(o0) | (((unsigned int)f2bfbits(o1)) << 16);
    reinterpret_cast<unsigned int*>(acc_out)[(size_t)node * 64 + lane] = pk;
}

// ---------- launch ----------
extern "C" void kernel_launch(void* const* d_in, const int* in_sizes, int n_in,
                              void* d_out, int out_size, void* d_ws, size_t ws_size,
                              hipStream_t stream)
{
    const float* feats = (const float*)d_in[0];
    const int*   ei    = (const int*)d_in[1];
    const float* Wq = (const float*)d_in[3];
    const float* bq = (const float*)d_in[4];
    const float* Wk = (const float*)d_in[5];
    const float* bk = (const float*)d_in[6];
    const float* Wv = (const float*)d_in[7];
    const float* bv = (const float*)d_in[8];
    const float* Wo = (const float*)d_in[9];
    const float* bo = (const float*)d_in[10];
    float* out = (float*)d_out;

    const int N = in_sizes[0] / 128;
    const int E = in_sizes[1] / 2;
    const int nb = (N + 1023) / 1024;

    char* ws = (char*)d_ws;
    size_t off = 0;
    auto alloc = [&](size_t bytes) -> void* {
        void* p = ws + off;
        off += (bytes + 255) & ~(size_t)255;
        return p;
    };
    unsigned short* qb   = (unsigned short*)alloc((size_t)N * 128 * 2);
    unsigned short* kb   = (unsigned short*)alloc((size_t)N * 128 * 2);
    unsigned short* vb   = (unsigned short*)alloc((size_t)N * 128 * 2);
    unsigned short* accb = (unsigned short*)alloc((size_t)N * 128 * 2);
    int* counts   = (int*)alloc(((size_t)N + 1 + N) * 4);
    int* fill     = counts + (N + 1);
    int* offsets  = (int*)alloc(((size_t)N + 1) * 4);
    int* sorted_r = (int*)alloc((size_t)E * 4);
    int* blkSum   = (int*)alloc(256 * 4);
    int* blkOff   = (int*)alloc(256 * 4);

    hipMemsetAsync(counts, 0, ((size_t)N + 1 + N) * 4, stream);

    hist_kernel<<<(E + 255) / 256, 256, 0, stream>>>(ei, counts, E);
    scan1_kernel<<<nb, 1024, 0, stream>>>(counts, offsets, blkSum, N);
    scan2_kernel<<<1, 64, 0, stream>>>(blkSum, blkOff, offsets, nb, N);
    scan3_kernel<<<nb, 1024, 0, stream>>>(offsets, blkOff, N);
    scatter_kernel<<<(E + 255) / 256, 256, 0, stream>>>(ei, offsets, fill, sorted_r, E);

    dim3 gq((N + 127) / 128, 2);
    qkv_gemm<<<gq, 256, 0, stream>>>(feats, Wq, bq, Wk, bk, Wv, bv, qb, kb, vb, N);

    edge_attn_kernel<<<(N + 3) / 4, 256, 0, stream>>>(qb, kb, vb, offsets, sorted_r, accb, N);

    out_gemm<<<gq, 256, 0, stream>>>(accb, Wo, bo, out, N);
}

// Round 3
// 436.274 us; speedup vs baseline: 1.5872x; 1.1510x over previous
//
#include <hip/hip_runtime.h>
#include <hip/hip_bf16.h>

typedef __attribute__((ext_vector_type(8))) short bh8;
typedef __attribute__((ext_vector_type(4))) float f32x4;

__device__ __forceinline__ float bfbits2f(unsigned short s) {
    union { unsigned int u; float f; } cv;
    cv.u = ((unsigned int)s) << 16;
    return cv.f;
}
__device__ __forceinline__ unsigned short f2bfbits(float f) {
    union { float f; unsigned int u; } cv; cv.f = f;
    unsigned int u = cv.u;
    u += 0x7fffu + ((u >> 16) & 1u);   // round-to-nearest-even
    return (unsigned short)(u >> 16);
}
__device__ __forceinline__ unsigned int pack2bf(float a, float b) {
    return (unsigned int)f2bfbits(a) | (((unsigned int)f2bfbits(b)) << 16);
}

// load 8 consecutive fp32, convert to a bf16x8 MFMA fragment
__device__ __forceinline__ bh8 load_frag_f32(const float* __restrict__ p) {
    float4 f0 = *reinterpret_cast<const float4*>(p);
    float4 f1 = *reinterpret_cast<const float4*>(p + 4);
    bh8 r;
    r[0] = (short)f2bfbits(f0.x); r[1] = (short)f2bfbits(f0.y);
    r[2] = (short)f2bfbits(f0.z); r[3] = (short)f2bfbits(f0.w);
    r[4] = (short)f2bfbits(f1.x); r[5] = (short)f2bfbits(f1.y);
    r[6] = (short)f2bfbits(f1.z); r[7] = (short)f2bfbits(f1.w);
    return r;
}

// ---------- W fp32 -> bf16 pre-conversion (4 matrices of 128x128) ----------
__global__ __launch_bounds__(256)
void wconv_kernel(const float* __restrict__ w0, const float* __restrict__ w1,
                  const float* __restrict__ w2, const float* __restrict__ w3,
                  unsigned short* __restrict__ o0, unsigned short* __restrict__ o1,
                  unsigned short* __restrict__ o2, unsigned short* __restrict__ o3)
{
    const float* src[4] = {w0, w1, w2, w3};
    unsigned short* dst[4] = {o0, o1, o2, o3};
    const float* s = src[blockIdx.y];
    unsigned short* d = dst[blockIdx.y];
    int i = (blockIdx.x * 256 + threadIdx.x) * 4;   // 16 blocks x 256 thr x 4 = 16384
    float4 f = *reinterpret_cast<const float4*>(&s[i]);
    uint2 p;
    p.x = pack2bf(f.x, f.y);
    p.y = pack2bf(f.z, f.w);
    *reinterpret_cast<uint2*>(&d[i]) = p;
}

// ---------- fused QKV GEMM (MFMA, swapped operands for packed stores) ----------
// block 256 = 4 waves; block tile 128 rows; wave w handles rows bx*128+w*32..+31,
// all 128 output cols, for q,k,v sequentially.
// mfma(b=W-rows, a=A-rows): out lane&15 = A-row, (lane>>4)*4+reg = W-col (4 consecutive).
__global__ __launch_bounds__(256)
void qkv_gemm(const float* __restrict__ A,
              const unsigned short* __restrict__ Wqb, const float* __restrict__ bq,
              const unsigned short* __restrict__ Wkb, const float* __restrict__ bk,
              const unsigned short* __restrict__ Wvb, const float* __restrict__ bv,
              unsigned short* __restrict__ Oq, unsigned short* __restrict__ Ok,
              unsigned short* __restrict__ Ov, int M)
{
    const int lane = threadIdx.x & 63;
    const int w    = threadIdx.x >> 6;
    const int r0   = blockIdx.x * 128 + w * 32;
    const int lr   = lane & 15;
    const int lk   = (lane >> 4) * 8;     // k-octet within 32
    const int cq   = (lane >> 4) * 4;     // 4-col group within 16 (epilogue)

    // A fragments: 2 row-tiles x 4 k-steps, fp32->bf16 in-register
    bh8 a[2][4];
    #pragma unroll
    for (int jt = 0; jt < 2; jt++) {
        int row = r0 + jt * 16 + lr; if (row >= M) row = M - 1;
        const float* ap = &A[(size_t)row * 128 + lk];
        #pragma unroll
        for (int ks = 0; ks < 4; ks++) a[jt][ks] = load_frag_f32(ap + ks * 32);
    }

    const unsigned short* Ws[3] = {Wqb, Wkb, Wvb};
    const float* Bs[3] = {bq, bk, bv};
    unsigned short* Os[3] = {Oq, Ok, Ov};

    #pragma unroll
    for (int wsel = 0; wsel < 3; wsel++) {
        const unsigned short* W = Ws[wsel];
        f32x4 acc[2][8];
        #pragma unroll
        for (int jt = 0; jt < 2; jt++)
            #pragma unroll
            for (int it = 0; it < 8; it++)
                #pragma unroll
                for (int q = 0; q < 4; q++) acc[jt][it][q] = 0.f;

        #pragma unroll
        for (int ks = 0; ks < 4; ks++) {
            bh8 b[8];
            #pragma unroll
            for (int it = 0; it < 8; it++)
                b[it] = *reinterpret_cast<const bh8*>(
                    &W[(size_t)(it * 16 + lr) * 128 + ks * 32 + lk]);
            #pragma unroll
            for (int jt = 0; jt < 2; jt++)
                #pragma unroll
                for (int it = 0; it < 8; it++)
                    acc[jt][it] = __builtin_amdgcn_mfma_f32_16x16x32_bf16(
                        b[it], a[jt][ks], acc[jt][it], 0, 0, 0);
        }

        const float* bias = Bs[wsel];
        unsigned short* O = Os[wsel];
        #pragma unroll
        for (int jt = 0; jt < 2; jt++) {
            int row = r0 + jt * 16 + lr;
            if (row >= M) continue;
            #pragma unroll
            for (int it = 0; it < 8; it++) {
                float4 b4 = *reinterpret_cast<const float4*>(&bias[it * 16 + cq]);
                uint2 pk;
                pk.x = pack2bf(acc[jt][it][0] + b4.x, acc[jt][it][1] + b4.y);
                pk.y = pack2bf(acc[jt][it][2] + b4.z, acc[jt][it][3] + b4.w);
                *reinterpret_cast<uint2*>(&O[(size_t)row * 128 + it * 16 + cq]) = pk;
            }
        }
    }
}

// ---------- output GEMM: out[M,128] = accb(bf16) @ Wo.T + bo, fp32 out ----------
__global__ __launch_bounds__(256)
void out_gemm(const unsigned short* __restrict__ A, const unsigned short* __restrict__ Wb,
              const float* __restrict__ bias, float* __restrict__ O, int M)
{
    const int lane = threadIdx.x & 63;
    const int w    = threadIdx.x >> 6;
    const int r0   = blockIdx.x * 128 + w * 32;
    const int lr   = lane & 15;
    const int lk   = (lane >> 4) * 8;
    const int cq   = (lane >> 4) * 4;

    bh8 a[2][4];
    #pragma unroll
    for (int jt = 0; jt < 2; jt++) {
        int row = r0 + jt * 16 + lr; if (row >= M) row = M - 1;
        const unsigned short* ap = &A[(size_t)row * 128 + lk];
        #pragma unroll
        for (int ks = 0; ks < 4; ks++)
            a[jt][ks] = *reinterpret_cast<const bh8*>(ap + ks * 32);
    }

    f32x4 acc[2][8];
    #pragma unroll
    for (int jt = 0; jt < 2; jt++)
        #pragma unroll
        for (int it = 0; it < 8; it++)
            #pragma unroll
            for (int q = 0; q < 4; q++) acc[jt][it][q] = 0.f;

    #pragma unroll
    for (int ks = 0; ks < 4; ks++) {
        bh8 b[8];
        #pragma unroll
        for (int it = 0; it < 8; it++)
            b[it] = *reinterpret_cast<const bh8*>(
                &Wb[(size_t)(it * 16 + lr) * 128 + ks * 32 + lk]);
        #pragma unroll
        for (int jt = 0; jt < 2; jt++)
            #pragma unroll
            for (int it = 0; it < 8; it++)
                acc[jt][it] = __builtin_amdgcn_mfma_f32_16x16x32_bf16(
                    b[it], a[jt][ks], acc[jt][it], 0, 0, 0);
    }

    #pragma unroll
    for (int jt = 0; jt < 2; jt++) {
        int row = r0 + jt * 16 + lr;
        if (row >= M) continue;
        #pragma unroll
        for (int it = 0; it < 8; it++) {
            float4 b4 = *reinterpret_cast<const float4*>(&bias[it * 16 + cq]);
            float4 o;
            o.x = acc[jt][it][0] + b4.x;
            o.y = acc[jt][it][1] + b4.y;
            o.z = acc[jt][it][2] + b4.z;
            o.w = acc[jt][it][3] + b4.w;
            *reinterpret_cast<float4*>(&O[(size_t)row * 128 + it * 16 + cq]) = o;
        }
    }
}

// ---------- CSR build ----------
__global__ void hist_kernel(const int* __restrict__ ei, int* __restrict__ counts, int E)
{
    int e = blockIdx.x * blockDim.x + threadIdx.x;
    if (e < E) atomicAdd(&counts[ei[2 * e + 1]], 1);
}

__device__ __forceinline__ int wave_incl_scan(int v, int lane) {
    #pragma unroll
    for (int off = 1; off < 64; off <<= 1) {
        int y = __shfl_up(v, off);
        if (lane >= off) v += y;
    }
    return v;
}

__global__ __launch_bounds__(1024)
void scan1_kernel(const int* __restrict__ counts, int* __restrict__ offs,
                  int* __restrict__ blkSum, int n)
{
    __shared__ int wsum[16];
    __shared__ int woff[16];
    const int t = threadIdx.x, lane = t & 63, w = t >> 6;
    int i = blockIdx.x * 1024 + t;
    int x = (i < n) ? counts[i] : 0;
    int v = wave_incl_scan(x, lane);
    if (lane == 63) wsum[w] = v;
    __syncthreads();
    if (t == 0) {
        int s = 0;
        #pragma unroll
        for (int j = 0; j < 16; j++) { int tmp = wsum[j]; woff[j] = s; s += tmp; }
        blkSum[blockIdx.x] = s;
    }
    __syncthreads();
    if (i < n) offs[i] = woff[w] + v - x;
}

__global__ void scan2_kernel(const int* __restrict__ blkSum, int* __restrict__ blkOff,
                             int* __restrict__ offs, int nb, int n)
{
    const int lane = threadIdx.x;   // 64 threads
    int carry = 0;
    for (int base = 0; base < nb; base += 64) {
        int x = (base + lane < nb) ? blkSum[base + lane] : 0;
        int v = wave_incl_scan(x, lane);
        if (base + lane < nb) blkOff[base + lane] = carry + v - x;
        carry += __shfl(v, 63);
    }
    if (lane == 0) offs[n] = carry;
}

__global__ __launch_bounds__(1024)
void scan3_kernel(int* __restrict__ offs, const int* __restrict__ blkOff, int n)
{
    int i = blockIdx.x * 1024 + threadIdx.x;
    if (i < n) offs[i] += blkOff[blockIdx.x];
}

__global__ void scatter_kernel(const int* __restrict__ ei, const int* __restrict__ offsets,
                               int* __restrict__ fill, int* __restrict__ sorted_r, int E)
{
    int e = blockIdx.x * blockDim.x + threadIdx.x;
    if (e < E) {
        int c = ei[2 * e + 1];
        int pos = offsets[c] + atomicAdd(&fill[c], 1);
        sorted_r[pos] = ei[2 * e];
    }
}

// ---------- edge attention: one wave per destination node ----------
__global__ __launch_bounds__(256)
void edge_attn_kernel(const unsigned short* __restrict__ qb,
                      const unsigned short* __restrict__ kb,
                      const unsigned short* __restrict__ vb,
                      const int* __restrict__ offsets,
                      const int* __restrict__ sorted_r,
                      unsigned short* __restrict__ acc_out, int n)
{
    const int lane = threadIdx.x & 63;
    const int wid  = threadIdx.x >> 6;
    const int node = blockIdx.x * 4 + wid;
    if (node >= n) return;

    const int h    = lane & 7;
    const int eloc = lane >> 3;
    const int seg0 = offsets[node];
    const int segL = offsets[node + 1] - seg0;

    float qf[16];
    {
        const uint4* p = reinterpret_cast<const uint4*>(&qb[(size_t)node * 128 + h * 16]);
        uint4 u0 = p[0], u1 = p[1];
        unsigned int uu[8] = {u0.x, u0.y, u0.z, u0.w, u1.x, u1.y, u1.z, u1.w};
        #pragma unroll
        for (int i = 0; i < 8; i++) {
            qf[2 * i]     = bfbits2f((unsigned short)(uu[i] & 0xffffu));
            qf[2 * i + 1] = bfbits2f((unsigned short)(uu[i] >> 16));
        }
    }

    float acc0 = 0.f, acc1 = 0.f, ssum = 0.f;
    for (int base = 0; base < segL; base += 8) {
        int idx = base + eloc;
        bool valid = idx < segL;
        int r = valid ? sorted_r[seg0 + idx] : 0;

        float ex = 0.f;
        {
            const uint4* p = reinterpret_cast<const uint4*>(&kb[(size_t)r * 128 + h * 16]);
            uint4 u0 = p[0], u1 = p[1];
            unsigned int uu[8] = {u0.x, u0.y, u0.z, u0.w, u1.x, u1.y, u1.z, u1.w};
            float s = 0.f;
            #pragma unroll
            for (int i = 0; i < 8; i++) {
                s += qf[2 * i]     * bfbits2f((unsigned short)(uu[i] & 0xffffu));
                s += qf[2 * i + 1] * bfbits2f((unsigned short)(uu[i] >> 16));
            }
            ex = valid ? __expf(s * 0.25f) : 0.f;
        }
        ssum += ex;

        int ecnt = segL - base; if (ecnt > 8) ecnt = 8;
        for (int e = 0; e < ecnt; e++) {
            float exv = __shfl(ex, e * 8 + (lane >> 3));
            int   re  = __shfl(r, e * 8);
            unsigned int u = *reinterpret_cast<const unsigned int*>(&vb[(size_t)re * 128 + 2 * lane]);
            acc0 += exv * bfbits2f((unsigned short)(u & 0xffffu));
            acc1 += exv * bfbits2f((unsigned short)(u >> 16));
        }
    }

    ssum += __shfl_xor(ssum, 8);
    ssum += __shfl_xor(ssum, 16);
    ssum += __shfl_xor(ssum, 32);
    float den = __shfl(ssum, lane >> 3) + 1e-16f;

    reinterpret_cast<unsigned int*>(acc_out)[(size_t)node * 64 + lane] =
        pack2bf(acc0 / den, acc1 / den);
}

// ---------- launch ----------
extern "C" void kernel_launch(void* const* d_in, const int* in_sizes, int n_in,
                              void* d_out, int out_size, void* d_ws, size_t ws_size,
                              hipStream_t stream)
{
    const float* feats = (const float*)d_in[0];
    const int*   ei    = (const int*)d_in[1];
    const float* Wq = (const float*)d_in[3];
    const float* bq = (const float*)d_in[4];
    const float* Wk = (const float*)d_in[5];
    const float* bk = (const float*)d_in[6];
    const float* Wv = (const float*)d_in[7];
    const float* bv = (const float*)d_in[8];
    const float* Wo = (const float*)d_in[9];
    const float* bo = (const float*)d_in[10];
    float* out = (float*)d_out;

    const int N = in_sizes[0] / 128;
    const int E = in_sizes[1] / 2;
    const int nb = (N + 1023) / 1024;

    char* ws = (char*)d_ws;
    size_t off = 0;
    auto alloc = [&](size_t bytes) -> void* {
        void* p = ws + off;
        off += (bytes + 255) & ~(size_t)255;
        return p;
    };
    unsigned short* qb   = (unsigned short*)alloc((size_t)N * 128 * 2);
    unsigned short* kb   = (unsigned short*)alloc((size_t)N * 128 * 2);
    unsigned short* vb   = (unsigned short*)alloc((size_t)N * 128 * 2);
    unsigned short* accb = (unsigned short*)alloc((size_t)N * 128 * 2);
    int* counts   = (int*)alloc(((size_t)N + 1 + N) * 4);
    int* fill     = counts + (N + 1);
    int* offsets  = (int*)alloc(((size_t)N + 1) * 4);
    int* sorted_r = (int*)alloc((size_t)E * 4);
    int* blkSum   = (int*)alloc(256 * 4);
    int* blkOff   = (int*)alloc(256 * 4);
    unsigned short* Wqb = (unsigned short*)alloc(128 * 128 * 2);
    unsigned short* Wkb = (unsigned short*)alloc(128 * 128 * 2);
    unsigned short* Wvb = (unsigned short*)alloc(128 * 128 * 2);
    unsigned short* Wob = (unsigned short*)alloc(128 * 128 * 2);

    hipMemsetAsync(counts, 0, ((size_t)N + 1 + N) * 4, stream);

    wconv_kernel<<<dim3(16, 4), 256, 0, stream>>>(Wq, Wk, Wv, Wo, Wqb, Wkb, Wvb, Wob);

    hist_kernel<<<(E + 255) / 256, 256, 0, stream>>>(ei, counts, E);
    scan1_kernel<<<nb, 1024, 0, stream>>>(counts, offsets, blkSum, N);
    scan2_kernel<<<1, 64, 0, stream>>>(blkSum, blkOff, offsets, nb, N);
    scan3_kernel<<<nb, 1024, 0, stream>>>(offsets, blkOff, N);
    scatter_kernel<<<(E + 255) / 256, 256, 0, stream>>>(ei, offsets, fill, sorted_r, E);

    const int gx = (N + 127) / 128;
    qkv_gemm<<<gx, 256, 0, stream>>>(feats, Wqb, bq, Wkb, bk, Wvb, bv, qb, kb, vb, N);

    edge_attn_kernel<<<(N + 3) / 4, 256, 0, stream>>>(qb, kb, vb, offsets, sorted_r, accb, N);

    out_gemm<<<gx, 256, 0, stream>>>(accb, Wob, bo, out, N);
}

// Round 4
// 400.502 us; speedup vs baseline: 1.7290x; 1.0893x over previous
//
#include <hip/hip_runtime.h>
#include <hip/hip_bf16.h>

typedef __attribute__((ext_vector_type(8))) short bh8;
typedef __attribute__((ext_vector_type(4))) float f32x4;

__device__ __forceinline__ float bfbits2f(unsigned short s) {
    union { unsigned int u; float f; } cv;
    cv.u = ((unsigned int)s) << 16;
    return cv.f;
}
__device__ __forceinline__ unsigned short f2bfbits(float f) {
    union { float f; unsigned int u; } cv; cv.f = f;
    unsigned int u = cv.u;
    u += 0x7fffu + ((u >> 16) & 1u);   // round-to-nearest-even
    return (unsigned short)(u >> 16);
}
__device__ __forceinline__ unsigned int pack2bf(float a, float b) {
    return (unsigned int)f2bfbits(a) | (((unsigned int)f2bfbits(b)) << 16);
}

// load 8 consecutive fp32, convert to a bf16x8 MFMA fragment
__device__ __forceinline__ bh8 load_frag_f32(const float* __restrict__ p) {
    float4 f0 = *reinterpret_cast<const float4*>(p);
    float4 f1 = *reinterpret_cast<const float4*>(p + 4);
    bh8 r;
    r[0] = (short)f2bfbits(f0.x); r[1] = (short)f2bfbits(f0.y);
    r[2] = (short)f2bfbits(f0.z); r[3] = (short)f2bfbits(f0.w);
    r[4] = (short)f2bfbits(f1.x); r[5] = (short)f2bfbits(f1.y);
    r[6] = (short)f2bfbits(f1.z); r[7] = (short)f2bfbits(f1.w);
    return r;
}

// ---------- W fp32 -> bf16 pre-conversion (4 matrices of 128x128) ----------
__global__ __launch_bounds__(256)
void wconv_kernel(const float* __restrict__ w0, const float* __restrict__ w1,
                  const float* __restrict__ w2, const float* __restrict__ w3,
                  unsigned short* __restrict__ o0, unsigned short* __restrict__ o1,
                  unsigned short* __restrict__ o2, unsigned short* __restrict__ o3)
{
    const float* src[4] = {w0, w1, w2, w3};
    unsigned short* dst[4] = {o0, o1, o2, o3};
    const float* s = src[blockIdx.y];
    unsigned short* d = dst[blockIdx.y];
    int i = (blockIdx.x * 256 + threadIdx.x) * 4;
    float4 f = *reinterpret_cast<const float4*>(&s[i]);
    uint2 p;
    p.x = pack2bf(f.x, f.y);
    p.y = pack2bf(f.z, f.w);
    *reinterpret_cast<uint2*>(&d[i]) = p;
}

// ---------- fused QKV GEMM (MFMA, swapped operands for packed stores) ----------
__global__ __launch_bounds__(256)
void qkv_gemm(const float* __restrict__ A,
              const unsigned short* __restrict__ Wqb, const float* __restrict__ bq,
              const unsigned short* __restrict__ Wkb, const float* __restrict__ bk,
              const unsigned short* __restrict__ Wvb, const float* __restrict__ bv,
              unsigned short* __restrict__ Oq, unsigned short* __restrict__ Ok,
              unsigned short* __restrict__ Ov, int M)
{
    const int lane = threadIdx.x & 63;
    const int w    = threadIdx.x >> 6;
    const int r0   = blockIdx.x * 128 + w * 32;
    const int lr   = lane & 15;
    const int lk   = (lane >> 4) * 8;
    const int cq   = (lane >> 4) * 4;

    bh8 a[2][4];
    #pragma unroll
    for (int jt = 0; jt < 2; jt++) {
        int row = r0 + jt * 16 + lr; if (row >= M) row = M - 1;
        const float* ap = &A[(size_t)row * 128 + lk];
        #pragma unroll
        for (int ks = 0; ks < 4; ks++) a[jt][ks] = load_frag_f32(ap + ks * 32);
    }

    const unsigned short* Ws[3] = {Wqb, Wkb, Wvb};
    const float* Bs[3] = {bq, bk, bv};
    unsigned short* Os[3] = {Oq, Ok, Ov};

    #pragma unroll
    for (int wsel = 0; wsel < 3; wsel++) {
        const unsigned short* W = Ws[wsel];
        f32x4 acc[2][8];
        #pragma unroll
        for (int jt = 0; jt < 2; jt++)
            #pragma unroll
            for (int it = 0; it < 8; it++)
                #pragma unroll
                for (int q = 0; q < 4; q++) acc[jt][it][q] = 0.f;

        #pragma unroll
        for (int ks = 0; ks < 4; ks++) {
            bh8 b[8];
            #pragma unroll
            for (int it = 0; it < 8; it++)
                b[it] = *reinterpret_cast<const bh8*>(
                    &W[(size_t)(it * 16 + lr) * 128 + ks * 32 + lk]);
            #pragma unroll
            for (int jt = 0; jt < 2; jt++)
                #pragma unroll
                for (int it = 0; it < 8; it++)
                    acc[jt][it] = __builtin_amdgcn_mfma_f32_16x16x32_bf16(
                        b[it], a[jt][ks], acc[jt][it], 0, 0, 0);
        }

        const float* bias = Bs[wsel];
        unsigned short* O = Os[wsel];
        #pragma unroll
        for (int jt = 0; jt < 2; jt++) {
            int row = r0 + jt * 16 + lr;
            if (row >= M) continue;
            #pragma unroll
            for (int it = 0; it < 8; it++) {
                float4 b4 = *reinterpret_cast<const float4*>(&bias[it * 16 + cq]);
                uint2 pk;
                pk.x = pack2bf(acc[jt][it][0] + b4.x, acc[jt][it][1] + b4.y);
                pk.y = pack2bf(acc[jt][it][2] + b4.z, acc[jt][it][3] + b4.w);
                *reinterpret_cast<uint2*>(&O[(size_t)row * 128 + it * 16 + cq]) = pk;
            }
        }
    }
}

// ---------- output GEMM: out[M,128] = accb(bf16) @ Wo.T + bo, fp32 out ----------
__global__ __launch_bounds__(256)
void out_gemm(const unsigned short* __restrict__ A, const unsigned short* __restrict__ Wb,
              const float* __restrict__ bias, float* __restrict__ O, int M)
{
    const int lane = threadIdx.x & 63;
    const int w    = threadIdx.x >> 6;
    const int r0   = blockIdx.x * 128 + w * 32;
    const int lr   = lane & 15;
    const int lk   = (lane >> 4) * 8;
    const int cq   = (lane >> 4) * 4;

    bh8 a[2][4];
    #pragma unroll
    for (int jt = 0; jt < 2; jt++) {
        int row = r0 + jt * 16 + lr; if (row >= M) row = M - 1;
        const unsigned short* ap = &A[(size_t)row * 128 + lk];
        #pragma unroll
        for (int ks = 0; ks < 4; ks++)
            a[jt][ks] = *reinterpret_cast<const bh8*>(ap + ks * 32);
    }

    f32x4 acc[2][8];
    #pragma unroll
    for (int jt = 0; jt < 2; jt++)
        #pragma unroll
        for (int it = 0; it < 8; it++)
            #pragma unroll
            for (int q = 0; q < 4; q++) acc[jt][it][q] = 0.f;

    #pragma unroll
    for (int ks = 0; ks < 4; ks++) {
        bh8 b[8];
        #pragma unroll
        for (int it = 0; it < 8; it++)
            b[it] = *reinterpret_cast<const bh8*>(
                &Wb[(size_t)(it * 16 + lr) * 128 + ks * 32 + lk]);
        #pragma unroll
        for (int jt = 0; jt < 2; jt++)
            #pragma unroll
            for (int it = 0; it < 8; it++)
                acc[jt][it] = __builtin_amdgcn_mfma_f32_16x16x32_bf16(
                    b[it], a[jt][ks], acc[jt][it], 0, 0, 0);
    }

    #pragma unroll
    for (int jt = 0; jt < 2; jt++) {
        int row = r0 + jt * 16 + lr;
        if (row >= M) continue;
        #pragma unroll
        for (int it = 0; it < 8; it++) {
            float4 b4 = *reinterpret_cast<const float4*>(&bias[it * 16 + cq]);
            float4 o;
            o.x = acc[jt][it][0] + b4.x;
            o.y = acc[jt][it][1] + b4.y;
            o.z = acc[jt][it][2] + b4.z;
            o.w = acc[jt][it][3] + b4.w;
            *reinterpret_cast<float4*>(&O[(size_t)row * 128 + it * 16 + cq]) = o;
        }
    }
}

// ---------- CSR build ----------
__global__ void hist_kernel(const int* __restrict__ ei, int* __restrict__ counts, int E)
{
    int e = blockIdx.x * blockDim.x + threadIdx.x;
    if (e < E) atomicAdd(&counts[ei[2 * e + 1]], 1);
}

__device__ __forceinline__ int wave_incl_scan(int v, int lane) {
    #pragma unroll
    for (int off = 1; off < 64; off <<= 1) {
        int y = __shfl_up(v, off);
        if (lane >= off) v += y;
    }
    return v;
}

__global__ __launch_bounds__(1024)
void scan1_kernel(const int* __restrict__ counts, int* __restrict__ offs,
                  int* __restrict__ blkSum, int n)
{
    __shared__ int wsum[16];
    __shared__ int woff[16];
    const int t = threadIdx.x, lane = t & 63, w = t >> 6;
    int i = blockIdx.x * 1024 + t;
    int x = (i < n) ? counts[i] : 0;
    int v = wave_incl_scan(x, lane);
    if (lane == 63) wsum[w] = v;
    __syncthreads();
    if (t == 0) {
        int s = 0;
        #pragma unroll
        for (int j = 0; j < 16; j++) { int tmp = wsum[j]; woff[j] = s; s += tmp; }
        blkSum[blockIdx.x] = s;
    }
    __syncthreads();
    if (i < n) offs[i] = woff[w] + v - x;
}

__global__ void scan2_kernel(const int* __restrict__ blkSum, int* __restrict__ blkOff,
                             int* __restrict__ offs, int nb, int n)
{
    const int lane = threadIdx.x;   // 64 threads
    int carry = 0;
    for (int base = 0; base < nb; base += 64) {
        int x = (base + lane < nb) ? blkSum[base + lane] : 0;
        int v = wave_incl_scan(x, lane);
        if (base + lane < nb) blkOff[base + lane] = carry + v - x;
        carry += __shfl(v, 63);
    }
    if (lane == 0) offs[n] = carry;
}

__global__ __launch_bounds__(1024)
void scan3_kernel(int* __restrict__ offs, const int* __restrict__ blkOff, int n)
{
    int i = blockIdx.x * 1024 + threadIdx.x;
    if (i < n) offs[i] += blkOff[blockIdx.x];
}

__global__ void scatter_kernel(const int* __restrict__ ei, const int* __restrict__ offsets,
                               int* __restrict__ fill, int* __restrict__ sorted_r, int E)
{
    int e = blockIdx.x * blockDim.x + threadIdx.x;
    if (e < E) {
        int c = ei[2 * e + 1];
        int pos = offsets[c] + atomicAdd(&fill[c], 1);
        sorted_r[pos] = ei[2 * e];
    }
}

// ---------- edge attention: one wave per destination node, pipelined ----------
__global__ __launch_bounds__(256)
void edge_attn_kernel(const unsigned short* __restrict__ qb,
                      const unsigned short* __restrict__ kb,
                      const unsigned short* __restrict__ vb,
                      const int* __restrict__ offsets,
                      const int* __restrict__ sorted_r,
                      unsigned short* __restrict__ acc_out, int n)
{
    const int lane = threadIdx.x & 63;
    const int wid  = threadIdx.x >> 6;
    const int node = blockIdx.x * 4 + wid;
    if (node >= n) return;

    const int h    = lane & 7;    // head (score phase)
    const int eloc = lane >> 3;   // k-edge slot == head of owned dims (2*lane)
    const int seg0 = __builtin_amdgcn_readfirstlane(offsets[node]);
    const int segL = __builtin_amdgcn_readfirstlane(offsets[node + 1]) - seg0;
    const int nch  = (segL + 7) >> 3;
    const int* __restrict__ sr = sorted_r + seg0;

    // q fragment: q[node, h*16 .. h*16+15]
    float qf[16];
    {
        const uint4* p = reinterpret_cast<const uint4*>(&qb[(size_t)node * 128 + h * 16]);
        uint4 u0 = p[0], u1 = p[1];
        unsigned int uu[8] = {u0.x, u0.y, u0.z, u0.w, u1.x, u1.y, u1.z, u1.w};
        #pragma unroll
        for (int i = 0; i < 8; i++) {
            qf[2 * i]     = bfbits2f((unsigned short)(uu[i] & 0xffffu));
            qf[2 * i + 1] = bfbits2f((unsigned short)(uu[i] >> 16));
        }
    }

    float acc0 = 0.f, acc1 = 0.f, ssum = 0.f;

    uint4 kA0, kA1, kB0, kB1;
    unsigned int vA[8], vB[8];

    // prologue: chunk-0 k + v loads (addresses clamped into segment; ex=0 kills pads)
    if (nch > 0) {
        int idx = (eloc < segL) ? eloc : (segL - 1);
        int rk  = sr[idx];
        const uint4* kp = reinterpret_cast<const uint4*>(&kb[(size_t)rk * 128 + h * 16]);
        kA0 = kp[0]; kA1 = kp[1];
        int ec0 = (segL < 8) ? segL : 8;
        #pragma unroll
        for (int e = 0; e < 8; e++) {
            int re = sr[(e < ec0) ? e : (ec0 - 1)];   // uniform -> s_load
            vA[e] = *reinterpret_cast<const unsigned int*>(&vb[(size_t)re * 128 + 2 * lane]);
        }
    }

    auto step = [&](int c, const uint4& ck0, const uint4& ck1, const unsigned int (&cv)[8],
                    uint4& nk0, uint4& nk1, unsigned int (&nv)[8]) {
        const int base = c << 3;
        // prefetch chunk c+1 (k and v) before consuming chunk c
        if (c + 1 < nch) {
            int nb   = base + 8;
            int nidx = nb + eloc;
            int rk   = sr[(nidx < segL) ? nidx : (segL - 1)];
            const uint4* kp = reinterpret_cast<const uint4*>(&kb[(size_t)rk * 128 + h * 16]);
            nk0 = kp[0]; nk1 = kp[1];
            int ecn = segL - nb; if (ecn > 8) ecn = 8;
            #pragma unroll
            for (int e = 0; e < 8; e++) {
                int re = sr[nb + ((e < ecn) ? e : (ecn - 1))];
                nv[e] = *reinterpret_cast<const unsigned int*>(&vb[(size_t)re * 128 + 2 * lane]);
            }
        }
        // score for this lane's (edge eloc, head h)
        unsigned int uu[8] = {ck0.x, ck0.y, ck0.z, ck0.w, ck1.x, ck1.y, ck1.z, ck1.w};
        float s = 0.f;
        #pragma unroll
        for (int i = 0; i < 8; i++) {
            s += qf[2 * i]     * bfbits2f((unsigned short)(uu[i] & 0xffffu));
            s += qf[2 * i + 1] * bfbits2f((unsigned short)(uu[i] >> 16));
        }
        float ex = (base + eloc < segL) ? __expf(s * 0.25f) : 0.f;
        ssum += ex;
        // broadcast ex per edge, FMA with prefetched v
        #pragma unroll
        for (int e = 0; e < 8; e++) {
            float exv = __shfl(ex, e * 8 + eloc);   // eloc == head of owned dims
            acc0 += exv * bfbits2f((unsigned short)(cv[e] & 0xffffu));
            acc1 += exv * bfbits2f((unsigned short)(cv[e] >> 16));
        }
    };

    int c = 0;
    while (c < nch) {
        step(c, kA0, kA1, vA, kB0, kB1, vB); c++;
        if (c >= nch) break;
        step(c, kB0, kB1, vB, kA0, kA1, vA); c++;
    }

    // reduce ssum over edge slots (lane bits 3..5)
    ssum += __shfl_xor(ssum, 8);
    ssum += __shfl_xor(ssum, 16);
    ssum += __shfl_xor(ssum, 32);
    float den = __shfl(ssum, lane >> 3) + 1e-16f;
    float rd  = 1.0f / den;

    reinterpret_cast<unsigned int*>(acc_out)[(size_t)node * 64 + lane] =
        pack2bf(acc0 * rd, acc1 * rd);
}

// ---------- launch ----------
extern "C" void kernel_launch(void* const* d_in, const int* in_sizes, int n_in,
                              void* d_out, int out_size, void* d_ws, size_t ws_size,
                              hipStream_t stream)
{
    const float* feats = (const float*)d_in[0];
    const int*   ei    = (const int*)d_in[1];
    const float* Wq = (const float*)d_in[3];
    const float* bq = (const float*)d_in[4];
    const float* Wk = (const float*)d_in[5];
    const float* bk = (const float*)d_in[6];
    const float* Wv = (const float*)d_in[7];
    const float* bv = (const float*)d_in[8];
    const float* Wo = (const float*)d_in[9];
    const float* bo = (const float*)d_in[10];
    float* out = (float*)d_out;

    const int N = in_sizes[0] / 128;
    const int E = in_sizes[1] / 2;
    const int nb = (N + 1023) / 1024;

    char* ws = (char*)d_ws;
    size_t off = 0;
    auto alloc = [&](size_t bytes) -> void* {
        void* p = ws + off;
        off += (bytes + 255) & ~(size_t)255;
        return p;
    };
    unsigned short* qb   = (unsigned short*)alloc((size_t)N * 128 * 2);
    unsigned short* kb   = (unsigned short*)alloc((size_t)N * 128 * 2);
    unsigned short* vb   = (unsigned short*)alloc((size_t)N * 128 * 2);
    unsigned short* accb = (unsigned short*)alloc((size_t)N * 128 * 2);
    int* counts   = (int*)alloc(((size_t)N + 1 + N) * 4);
    int* fill     = counts + (N + 1);
    int* offsets  = (int*)alloc(((size_t)N + 1) * 4);
    int* sorted_r = (int*)alloc((size_t)E * 4);
    int* blkSum   = (int*)alloc(256 * 4);
    int* blkOff   = (int*)alloc(256 * 4);
    unsigned short* Wqb = (unsigned short*)alloc(128 * 128 * 2);
    unsigned short* Wkb = (unsigned short*)alloc(128 * 128 * 2);
    unsigned short* Wvb = (unsigned short*)alloc(128 * 128 * 2);
    unsigned short* Wob = (unsigned short*)alloc(128 * 128 * 2);

    hipMemsetAsync(counts, 0, ((size_t)N + 1 + N) * 4, stream);

    wconv_kernel<<<dim3(16, 4), 256, 0, stream>>>(Wq, Wk, Wv, Wo, Wqb, Wkb, Wvb, Wob);

    hist_kernel<<<(E + 255) / 256, 256, 0, stream>>>(ei, counts, E);
    scan1_kernel<<<nb, 1024, 0, stream>>>(counts, offsets, blkSum, N);
    scan2_kernel<<<1, 64, 0, stream>>>(blkSum, blkOff, offsets, nb, N);
    scan3_kernel<<<nb, 1024, 0, stream>>>(offsets, blkOff, N);
    scatter_kernel<<<(E + 255) / 256, 256, 0, stream>>>(ei, offsets, fill, sorted_r, E);

    const int gx = (N + 127) / 128;
    qkv_gemm<<<gx, 256, 0, stream>>>(feats, Wqb, bq, Wkb, bk, Wvb, bv, qb, kb, vb, N);

    edge_attn_kernel<<<(N + 3) / 4, 256, 0, stream>>>(qb, kb, vb, offsets, sorted_r, accb, N);

    out_gemm<<<gx, 256, 0, stream>>>(accb, Wob, bo, out, N);
}

// Round 5
// 302.634 us; speedup vs baseline: 2.2881x; 1.3234x over previous
//
#include <hip/hip_runtime.h>
#include <hip/hip_bf16.h>

typedef __attribute__((ext_vector_type(8))) short bh8;
typedef __attribute__((ext_vector_type(4))) float f32x4;

__device__ __forceinline__ float bfbits2f(unsigned short s) {
    union { unsigned int u; float f; } cv;
    cv.u = ((unsigned int)s) << 16;
    return cv.f;
}
__device__ __forceinline__ unsigned short f2bfbits(float f) {
    union { float f; unsigned int u; } cv; cv.f = f;
    unsigned int u = cv.u;
    u += 0x7fffu + ((u >> 16) & 1u);   // round-to-nearest-even
    return (unsigned short)(u >> 16);
}
__device__ __forceinline__ unsigned int pack2bf(float a, float b) {
    return (unsigned int)f2bfbits(a) | (((unsigned int)f2bfbits(b)) << 16);
}

// load 8 consecutive fp32, convert to a bf16x8 MFMA fragment
__device__ __forceinline__ bh8 load_frag_f32(const float* __restrict__ p) {
    float4 f0 = *reinterpret_cast<const float4*>(p);
    float4 f1 = *reinterpret_cast<const float4*>(p + 4);
    bh8 r;
    r[0] = (short)f2bfbits(f0.x); r[1] = (short)f2bfbits(f0.y);
    r[2] = (short)f2bfbits(f0.z); r[3] = (short)f2bfbits(f0.w);
    r[4] = (short)f2bfbits(f1.x); r[5] = (short)f2bfbits(f1.y);
    r[6] = (short)f2bfbits(f1.z); r[7] = (short)f2bfbits(f1.w);
    return r;
}

// ---------- W fp32 -> bf16 pre-conversion (4 matrices of 128x128) ----------
__global__ __launch_bounds__(256)
void wconv_kernel(const float* __restrict__ w0, const float* __restrict__ w1,
                  const float* __restrict__ w2, const float* __restrict__ w3,
                  unsigned short* __restrict__ o0, unsigned short* __restrict__ o1,
                  unsigned short* __restrict__ o2, unsigned short* __restrict__ o3)
{
    const float* src[4] = {w0, w1, w2, w3};
    unsigned short* dst[4] = {o0, o1, o2, o3};
    const float* s = src[blockIdx.y];
    unsigned short* d = dst[blockIdx.y];
    int i = (blockIdx.x * 256 + threadIdx.x) * 4;
    float4 f = *reinterpret_cast<const float4*>(&s[i]);
    uint2 p;
    p.x = pack2bf(f.x, f.y);
    p.y = pack2bf(f.z, f.w);
    *reinterpret_cast<uint2*>(&d[i]) = p;
}

// ---------- fused QKV GEMM + scatter (blockIdx split) ----------
// blocks [0, gx): MFMA QKV GEMM; blocks [gx, gx+nsb): atomic-free scatter.
__global__ __launch_bounds__(256)
void qkv_scatter(const float* __restrict__ A,
                 const unsigned short* __restrict__ Wqb, const float* __restrict__ bq,
                 const unsigned short* __restrict__ Wkb, const float* __restrict__ bk,
                 const unsigned short* __restrict__ Wvb, const float* __restrict__ bv,
                 unsigned short* __restrict__ Oq, unsigned short* __restrict__ Ok,
                 unsigned short* __restrict__ Ov, int M, int gx,
                 const int* __restrict__ ei, const int* __restrict__ offsets,
                 const int* __restrict__ rank, int* __restrict__ sorted_r,
                 int E, int nsb)
{
    if (blockIdx.x >= (unsigned)gx) {
        // ---- scatter path: no atomics, independent random 4B writes ----
        int sb = blockIdx.x - gx;
        int stride = nsb * 256;
        for (int e = sb * 256 + threadIdx.x; e < E; e += stride) {
            int2 rc = reinterpret_cast<const int2*>(ei)[e];
            sorted_r[offsets[rc.y] + rank[e]] = rc.x;
        }
        return;
    }

    const int lane = threadIdx.x & 63;
    const int w    = threadIdx.x >> 6;
    const int r0   = blockIdx.x * 128 + w * 32;
    const int lr   = lane & 15;
    const int lk   = (lane >> 4) * 8;
    const int cq   = (lane >> 4) * 4;

    bh8 a[2][4];
    #pragma unroll
    for (int jt = 0; jt < 2; jt++) {
        int row = r0 + jt * 16 + lr; if (row >= M) row = M - 1;
        const float* ap = &A[(size_t)row * 128 + lk];
        #pragma unroll
        for (int ks = 0; ks < 4; ks++) a[jt][ks] = load_frag_f32(ap + ks * 32);
    }

    const unsigned short* Ws[3] = {Wqb, Wkb, Wvb};
    const float* Bs[3] = {bq, bk, bv};
    unsigned short* Os[3] = {Oq, Ok, Ov};

    #pragma unroll
    for (int wsel = 0; wsel < 3; wsel++) {
        const unsigned short* W = Ws[wsel];
        f32x4 acc[2][8];
        #pragma unroll
        for (int jt = 0; jt < 2; jt++)
            #pragma unroll
            for (int it = 0; it < 8; it++)
                #pragma unroll
                for (int q = 0; q < 4; q++) acc[jt][it][q] = 0.f;

        #pragma unroll
        for (int ks = 0; ks < 4; ks++) {
            bh8 b[8];
            #pragma unroll
            for (int it = 0; it < 8; it++)
                b[it] = *reinterpret_cast<const bh8*>(
                    &W[(size_t)(it * 16 + lr) * 128 + ks * 32 + lk]);
            #pragma unroll
            for (int jt = 0; jt < 2; jt++)
                #pragma unroll
                for (int it = 0; it < 8; it++)
                    acc[jt][it] = __builtin_amdgcn_mfma_f32_16x16x32_bf16(
                        b[it], a[jt][ks], acc[jt][it], 0, 0, 0);
        }

        const float* bias = Bs[wsel];
        unsigned short* O = Os[wsel];
        #pragma unroll
        for (int jt = 0; jt < 2; jt++) {
            int row = r0 + jt * 16 + lr;
            if (row >= M) continue;
            #pragma unroll
            for (int it = 0; it < 8; it++) {
                float4 b4 = *reinterpret_cast<const float4*>(&bias[it * 16 + cq]);
                uint2 pk;
                pk.x = pack2bf(acc[jt][it][0] + b4.x, acc[jt][it][1] + b4.y);
                pk.y = pack2bf(acc[jt][it][2] + b4.z, acc[jt][it][3] + b4.w);
                *reinterpret_cast<uint2*>(&O[(size_t)row * 128 + it * 16 + cq]) = pk;
            }
        }
    }
}

// ---------- output GEMM: out[M,128] = accb(bf16) @ Wo.T + bo, fp32 out ----------
__global__ __launch_bounds__(256)
void out_gemm(const unsigned short* __restrict__ A, const unsigned short* __restrict__ Wb,
              const float* __restrict__ bias, float* __restrict__ O, int M)
{
    const int lane = threadIdx.x & 63;
    const int w    = threadIdx.x >> 6;
    const int r0   = blockIdx.x * 128 + w * 32;
    const int lr   = lane & 15;
    const int lk   = (lane >> 4) * 8;
    const int cq   = (lane >> 4) * 4;

    bh8 a[2][4];
    #pragma unroll
    for (int jt = 0; jt < 2; jt++) {
        int row = r0 + jt * 16 + lr; if (row >= M) row = M - 1;
        const unsigned short* ap = &A[(size_t)row * 128 + lk];
        #pragma unroll
        for (int ks = 0; ks < 4; ks++)
            a[jt][ks] = *reinterpret_cast<const bh8*>(ap + ks * 32);
    }

    f32x4 acc[2][8];
    #pragma unroll
    for (int jt = 0; jt < 2; jt++)
        #pragma unroll
        for (int it = 0; it < 8; it++)
            #pragma unroll
            for (int q = 0; q < 4; q++) acc[jt][it][q] = 0.f;

    #pragma unroll
    for (int ks = 0; ks < 4; ks++) {
        bh8 b[8];
        #pragma unroll
        for (int it = 0; it < 8; it++)
            b[it] = *reinterpret_cast<const bh8*>(
                &Wb[(size_t)(it * 16 + lr) * 128 + ks * 32 + lk]);
        #pragma unroll
        for (int jt = 0; jt < 2; jt++)
            #pragma unroll
            for (int it = 0; it < 8; it++)
                acc[jt][it] = __builtin_amdgcn_mfma_f32_16x16x32_bf16(
                    b[it], a[jt][ks], acc[jt][it], 0, 0, 0);
    }

    #pragma unroll
    for (int jt = 0; jt < 2; jt++) {
        int row = r0 + jt * 16 + lr;
        if (row >= M) continue;
        #pragma unroll
        for (int it = 0; it < 8; it++) {
            float4 b4 = *reinterpret_cast<const float4*>(&bias[it * 16 + cq]);
            float4 o;
            o.x = acc[jt][it][0] + b4.x;
            o.y = acc[jt][it][1] + b4.y;
            o.z = acc[jt][it][2] + b4.z;
            o.w = acc[jt][it][3] + b4.w;
            *reinterpret_cast<float4*>(&O[(size_t)row * 128 + it * 16 + cq]) = o;
        }
    }
}

// ---------- CSR build ----------
// hist also records each edge's ticket (rank within its destination segment)
__global__ void hist_kernel(const int* __restrict__ ei, int* __restrict__ counts,
                            int* __restrict__ rank, int E)
{
    int e = blockIdx.x * blockDim.x + threadIdx.x;
    if (e < E) {
        int2 rc = reinterpret_cast<const int2*>(ei)[e];
        rank[e] = atomicAdd(&counts[rc.y], 1);
    }
}

__device__ __forceinline__ int wave_incl_scan(int v, int lane) {
    #pragma unroll
    for (int off = 1; off < 64; off <<= 1) {
        int y = __shfl_up(v, off);
        if (lane >= off) v += y;
    }
    return v;
}

__global__ __launch_bounds__(1024)
void scan1_kernel(const int* __restrict__ counts, int* __restrict__ offs,
                  int* __restrict__ blkSum, int n)
{
    __shared__ int wsum[16];
    __shared__ int woff[16];
    const int t = threadIdx.x, lane = t & 63, w = t >> 6;
    int i = blockIdx.x * 1024 + t;
    int x = (i < n) ? counts[i] : 0;
    int v = wave_incl_scan(x, lane);
    if (lane == 63) wsum[w] = v;
    __syncthreads();
    if (t == 0) {
        int s = 0;
        #pragma unroll
        for (int j = 0; j < 16; j++) { int tmp = wsum[j]; woff[j] = s; s += tmp; }
        blkSum[blockIdx.x] = s;
    }
    __syncthreads();
    if (i < n) offs[i] = woff[w] + v - x;
}

__global__ void scan2_kernel(const int* __restrict__ blkSum, int* __restrict__ blkOff,
                             int* __restrict__ offs, int nb, int n)
{
    const int lane = threadIdx.x;   // 64 threads
    int carry = 0;
    for (int base = 0; base < nb; base += 64) {
        int x = (base + lane < nb) ? blkSum[base + lane] : 0;
        int v = wave_incl_scan(x, lane);
        if (base + lane < nb) blkOff[base + lane] = carry + v - x;
        carry += __shfl(v, 63);
    }
    if (lane == 0) offs[n] = carry;
}

__global__ __launch_bounds__(1024)
void scan3_kernel(int* __restrict__ offs, const int* __restrict__ blkOff, int n)
{
    int i = blockIdx.x * 1024 + threadIdx.x;
    if (i < n) offs[i] += blkOff[blockIdx.x];
}

// ---------- edge attention: one wave per destination node, pipelined ----------
__global__ __launch_bounds__(256)
void edge_attn_kernel(const unsigned short* __restrict__ qb,
                      const unsigned short* __restrict__ kb,
                      const unsigned short* __restrict__ vb,
                      const int* __restrict__ offsets,
                      const int* __restrict__ sorted_r,
                      unsigned short* __restrict__ acc_out, int n)
{
    const int lane = threadIdx.x & 63;
    const int wid  = threadIdx.x >> 6;
    const int node = blockIdx.x * 4 + wid;
    if (node >= n) return;

    const int h    = lane & 7;    // head (score phase)
    const int eloc = lane >> 3;   // k-edge slot == head of owned dims (2*lane)
    const int seg0 = __builtin_amdgcn_readfirstlane(offsets[node]);
    const int segL = __builtin_amdgcn_readfirstlane(offsets[node + 1]) - seg0;
    const int nch  = (segL + 7) >> 3;
    const int* __restrict__ sr = sorted_r + seg0;

    float qf[16];
    {
        const uint4* p = reinterpret_cast<const uint4*>(&qb[(size_t)node * 128 + h * 16]);
        uint4 u0 = p[0], u1 = p[1];
        unsigned int uu[8] = {u0.x, u0.y, u0.z, u0.w, u1.x, u1.y, u1.z, u1.w};
        #pragma unroll
        for (int i = 0; i < 8; i++) {
            qf[2 * i]     = bfbits2f((unsigned short)(uu[i] & 0xffffu));
            qf[2 * i + 1] = bfbits2f((unsigned short)(uu[i] >> 16));
        }
    }

    float acc0 = 0.f, acc1 = 0.f, ssum = 0.f;

    uint4 kA0, kA1, kB0, kB1;
    unsigned int vA[8], vB[8];

    if (nch > 0) {
        int idx = (eloc < segL) ? eloc : (segL - 1);
        int rk  = sr[idx];
        const uint4* kp = reinterpret_cast<const uint4*>(&kb[(size_t)rk * 128 + h * 16]);
        kA0 = kp[0]; kA1 = kp[1];
        int ec0 = (segL < 8) ? segL : 8;
        #pragma unroll
        for (int e = 0; e < 8; e++) {
            int re = sr[(e < ec0) ? e : (ec0 - 1)];   // uniform -> s_load
            vA[e] = *reinterpret_cast<const unsigned int*>(&vb[(size_t)re * 128 + 2 * lane]);
        }
    }

    auto step = [&](int c, const uint4& ck0, const uint4& ck1, const unsigned int (&cv)[8],
                    uint4& nk0, uint4& nk1, unsigned int (&nv)[8]) {
        const int base = c << 3;
        if (c + 1 < nch) {
            int nb   = base + 8;
            int nidx = nb + eloc;
            int rk   = sr[(nidx < segL) ? nidx : (segL - 1)];
            const uint4* kp = reinterpret_cast<const uint4*>(&kb[(size_t)rk * 128 + h * 16]);
            nk0 = kp[0]; nk1 = kp[1];
            int ecn = segL - nb; if (ecn > 8) ecn = 8;
            #pragma unroll
            for (int e = 0; e < 8; e++) {
                int re = sr[nb + ((e < ecn) ? e : (ecn - 1))];
                nv[e] = *reinterpret_cast<const unsigned int*>(&vb[(size_t)re * 128 + 2 * lane]);
            }
        }
        unsigned int uu[8] = {ck0.x, ck0.y, ck0.z, ck0.w, ck1.x, ck1.y, ck1.z, ck1.w};
        float s = 0.f;
        #pragma unroll
        for (int i = 0; i < 8; i++) {
            s += qf[2 * i]     * bfbits2f((unsigned short)(uu[i] & 0xffffu));
            s += qf[2 * i + 1] * bfbits2f((unsigned short)(uu[i] >> 16));
        }
        float ex = (base + eloc < segL) ? __expf(s * 0.25f) : 0.f;
        ssum += ex;
        #pragma unroll
        for (int e = 0; e < 8; e++) {
            float exv = __shfl(ex, e * 8 + eloc);
            acc0 += exv * bfbits2f((unsigned short)(cv[e] & 0xffffu));
            acc1 += exv * bfbits2f((unsigned short)(cv[e] >> 16));
        }
    };

    int c = 0;
    while (c < nch) {
        step(c, kA0, kA1, vA, kB0, kB1, vB); c++;
        if (c >= nch) break;
        step(c, kB0, kB1, vB, kA0, kA1, vA); c++;
    }

    ssum += __shfl_xor(ssum, 8);
    ssum += __shfl_xor(ssum, 16);
    ssum += __shfl_xor(ssum, 32);
    float den = __shfl(ssum, lane >> 3) + 1e-16f;
    float rd  = 1.0f / den;

    reinterpret_cast<unsigned int*>(acc_out)[(size_t)node * 64 + lane] =
        pack2bf(acc0 * rd, acc1 * rd);
}

// ---------- launch ----------
extern "C" void kernel_launch(void* const* d_in, const int* in_sizes, int n_in,
                              void* d_out, int out_size, void* d_ws, size_t ws_size,
                              hipStream_t stream)
{
    const float* feats = (const float*)d_in[0];
    const int*   ei    = (const int*)d_in[1];
    const float* Wq = (const float*)d_in[3];
    const float* bq = (const float*)d_in[4];
    const float* Wk = (const float*)d_in[5];
    const float* bk = (const float*)d_in[6];
    const float* Wv = (const float*)d_in[7];
    const float* bv = (const float*)d_in[8];
    const float* Wo = (const float*)d_in[9];
    const float* bo = (const float*)d_in[10];
    float* out = (float*)d_out;

    const int N = in_sizes[0] / 128;
    const int E = in_sizes[1] / 2;
    const int nb = (N + 1023) / 1024;

    char* ws = (char*)d_ws;
    size_t off = 0;
    auto alloc = [&](size_t bytes) -> void* {
        void* p = ws + off;
        off += (bytes + 255) & ~(size_t)255;
        return p;
    };
    unsigned short* qb   = (unsigned short*)alloc((size_t)N * 128 * 2);
    unsigned short* kb   = (unsigned short*)alloc((size_t)N * 128 * 2);
    unsigned short* vb   = (unsigned short*)alloc((size_t)N * 128 * 2);
    unsigned short* accb = (unsigned short*)alloc((size_t)N * 128 * 2);
    int* rank     = (int*)accb;   // alias: rank's lifetime (hist->scatter) disjoint from accb's
    int* counts   = (int*)alloc(((size_t)N + 1) * 4);
    int* offsets  = (int*)alloc(((size_t)N + 1) * 4);
    int* sorted_r = (int*)alloc((size_t)E * 4);
    int* blkSum   = (int*)alloc(256 * 4);
    int* blkOff   = (int*)alloc(256 * 4);
    unsigned short* Wqb = (unsigned short*)alloc(128 * 128 * 2);
    unsigned short* Wkb = (unsigned short*)alloc(128 * 128 * 2);
    unsigned short* Wvb = (unsigned short*)alloc(128 * 128 * 2);
    unsigned short* Wob = (unsigned short*)alloc(128 * 128 * 2);

    hipMemsetAsync(counts, 0, ((size_t)N + 1) * 4, stream);

    wconv_kernel<<<dim3(16, 4), 256, 0, stream>>>(Wq, Wk, Wv, Wo, Wqb, Wkb, Wvb, Wob);

    hist_kernel<<<(E + 255) / 256, 256, 0, stream>>>(ei, counts, rank, E);
    scan1_kernel<<<nb, 1024, 0, stream>>>(counts, offsets, blkSum, N);
    scan2_kernel<<<1, 64, 0, stream>>>(blkSum, blkOff, offsets, nb, N);
    scan3_kernel<<<nb, 1024, 0, stream>>>(offsets, blkOff, N);

    const int gx  = (N + 127) / 128;
    const int nsb = 1024;
    qkv_scatter<<<gx + nsb, 256, 0, stream>>>(feats, Wqb, bq, Wkb, bk, Wvb, bv,
                                              qb, kb, vb, N, gx,
                                              ei, offsets, rank, sorted_r, E, nsb);

    edge_attn_kernel<<<(N + 3) / 4, 256, 0, stream>>>(qb, kb, vb, offsets, sorted_r, accb, N);

    out_gemm<<<gx, 256, 0, stream>>>(accb, Wob, bo, out, N);
}